// Round 7
// baseline (364.968 us; speedup 1.0000x reference)
//
#include <hip/hip_runtime.h>
#include <hip/hip_bf16.h>

#define SEQ   2048
#define HDIM  2048
#define NHEAD 16
#define HEADD 128
#define BATCH 2
#define MTOT  (BATCH*SEQ)   // 4096
#define BH    (BATCH*NHEAD) // 32

typedef __attribute__((ext_vector_type(8))) __bf16 bf16x8;
typedef __attribute__((ext_vector_type(4))) float f32x4;
typedef __attribute__((ext_vector_type(8))) unsigned short u16x8;

__device__ __forceinline__ unsigned short f2b(float f) {
    __bf16 h = (__bf16)f;
    return __builtin_bit_cast(unsigned short, h);
}

__device__ __forceinline__ void gld_lds16(const void* gptr, void* ldsptr) {
    __builtin_amdgcn_global_load_lds(
        (const __attribute__((address_space(1))) unsigned int*)gptr,
        (__attribute__((address_space(3))) unsigned int*)ldsptr,
        16, 0, 0);
}

// ---------------- f32 -> bf16 convert (vectorized, grid-stride) ----------------
__global__ void cvt_bf16(const float* __restrict__ src, unsigned short* __restrict__ dst, long n8) {
    long i = blockIdx.x * (long)blockDim.x + threadIdx.x;
    long stride = (long)gridDim.x * blockDim.x;
    for (; i < n8; i += stride) {
        f32x4 a = *(const f32x4*)(src + i * 8);
        f32x4 b = *(const f32x4*)(src + i * 8 + 4);
        u16x8 o;
#pragma unroll
        for (int j = 0; j < 4; ++j) { o[j] = f2b(a[j]); o[4 + j] = f2b(b[j]); }
        *(u16x8*)(dst + i * 8) = o;
    }
}

// fused 5-way convert
__global__ void cvt5(const float* __restrict__ s0, const float* __restrict__ s1,
                     const float* __restrict__ s2, const float* __restrict__ s3,
                     const float* __restrict__ s4,
                     unsigned short* __restrict__ d0, unsigned short* __restrict__ d1,
                     unsigned short* __restrict__ d2, unsigned short* __restrict__ d3,
                     unsigned short* __restrict__ d4,
                     long n0, long n1) {
    const float* s; unsigned short* d; long n;
    switch (blockIdx.z) {
        case 0: s = s0; d = d0; n = n0; break;
        case 1: s = s1; d = d1; n = n1; break;
        case 2: s = s2; d = d2; n = n1; break;
        case 3: s = s3; d = d3; n = n1; break;
        default: s = s4; d = d4; n = n1; break;
    }
    long i = blockIdx.x * (long)blockDim.x + threadIdx.x;
    long stride = (long)gridDim.x * blockDim.x;
    for (; i < n; i += stride) {
        f32x4 a = *(const f32x4*)(s + i * 8);
        f32x4 b = *(const f32x4*)(s + i * 8 + 4);
        u16x8 o;
#pragma unroll
        for (int j = 0; j < 4; ++j) { o[j] = f2b(a[j]); o[4 + j] = f2b(b[j]); }
        *(u16x8*)(d + i * 8) = o;
    }
}

// ---------------- GEMM: C[m][n] = A[m][:] . Bw[n][:] + bias[n]  (B^T layout) ----
// XCD-bijective block swizzle: each XCD gets a contiguous swz-chunk -> its
// 2 B-panels stay L2-resident (nwg=512, 512%8==0 -> simple form is bijective).
template <int MODE>
__launch_bounds__(256)
__global__ void gemm_bt(const unsigned short* __restrict__ A,
                        const unsigned short* __restrict__ Bw,
                        const float* __restrict__ bias,
                        void* __restrict__ Cout,
                        int Kc, float scale) {
    __shared__ unsigned short As[128 * 32];
    __shared__ unsigned short Bs[128 * 32];
    const int tid  = threadIdx.x;
    const int lane = tid & 63;
    const int w    = tid >> 6;

    const int wgid = blockIdx.y * gridDim.x + blockIdx.x;
    const int cpx  = (gridDim.x * gridDim.y) >> 3;
    const int swz  = (wgid & 7) * cpx + (wgid >> 3);
    const int m0 = (swz % gridDim.x) * 128, n0 = (swz / gridDim.x) * 128;

    const int wr = (w >> 1) * 64, wc = (w & 1) * 64;
    const long rowBytes = (long)Kc * 2;

    f32x4 acc[4][4] = {};

    const int kIters = Kc >> 5;
    for (int kt = 0; kt < kIters; ++kt) {
        const long kb = (long)kt * 64;
#pragma unroll
        for (int i = 0; i < 2; ++i) {
            int c = tid + i * 256;
            int row = c >> 2;
            int cb  = (c & 3) * 16;
            gld_lds16((const char*)A  + (long)(m0 + row) * rowBytes + kb + cb, (char*)As + c * 16);
            gld_lds16((const char*)Bw + (long)(n0 + row) * rowBytes + kb + cb, (char*)Bs + c * 16);
        }
        __syncthreads();
        bf16x8 af[4], bfr[4];
#pragma unroll
        for (int f = 0; f < 4; ++f) {
            af[f]  = *(const bf16x8*)&As[(wr + f * 16 + (lane & 15)) * 32 + (lane >> 4) * 8];
            bfr[f] = *(const bf16x8*)&Bs[(wc + f * 16 + (lane & 15)) * 32 + (lane >> 4) * 8];
        }
#pragma unroll
        for (int mf = 0; mf < 4; ++mf)
#pragma unroll
            for (int nf = 0; nf < 4; ++nf)
                acc[mf][nf] = __builtin_amdgcn_mfma_f32_16x16x32_bf16(af[mf], bfr[nf], acc[mf][nf], 0, 0, 0);
        __syncthreads();
    }

#pragma unroll
    for (int mf = 0; mf < 4; ++mf) {
#pragma unroll
        for (int nf = 0; nf < 4; ++nf) {
            int n = n0 + wc + nf * 16 + (lane & 15);
            float bv = bias[n];
#pragma unroll
            for (int j = 0; j < 4; ++j) {
                int m = m0 + wr + mf * 16 + (lane >> 4) * 4 + j;
                float v = (acc[mf][nf][j] + bv) * scale;
                if (MODE == 0) {
                    int b = m >> 11, s = m & 2047;
                    int nh = n >> 7, hd = n & 127;
                    ((unsigned short*)Cout)[((long)(b * NHEAD + nh) * SEQ + s) * HEADD + hd] = f2b(v);
                } else if (MODE == 1) {
                    int b = m >> 11, s = m & 2047;
                    int nh = n >> 7, hd = n & 127;
                    ((unsigned short*)Cout)[((long)(b * NHEAD + nh) * HEADD + hd) * SEQ + s] = f2b(v);
                } else {
                    ((float*)Cout)[(long)m * HDIM + n] = v;
                }
            }
        }
    }
}

// ---------------- causal flash attention (swapped-QK, fused hi/lo step) ------
// S^T = mfma(kf, qf): C col = q = lane&15 (lane-owned row), row = kv.
// PV:  O^T = mfma(vf, pf): C col = q, row = d.
// hi and lo q-paths share every kf/vf LDS read (identical offsets).

__device__ __forceinline__ void softmax_pack(
    f32x4 (&sv)[4], f32x4 (&acc)[8], float& mrun, float& lrun,
    unsigned short* Psw, int q, int G, bf16x8 (&pf)[2])
{
    float tmax = sv[0][0];
#pragma unroll
    for (int ct = 0; ct < 4; ++ct)
#pragma unroll
        for (int j = 0; j < 4; ++j) tmax = fmaxf(tmax, sv[ct][j]);
    tmax = fmaxf(tmax, __shfl_xor(tmax, 16));
    tmax = fmaxf(tmax, __shfl_xor(tmax, 32));

    float mnew = mrun, sc = 1.0f;
    if (__any(tmax > mrun + 8.0f)) {     // defer-max (T13)
        mnew = fmaxf(mrun, tmax);
        sc = __expf(mrun - mnew);
#pragma unroll
        for (int h8 = 0; h8 < 8; ++h8) acc[h8] *= sc;
    }
    float rs = 0.f;
#pragma unroll
    for (int ct = 0; ct < 4; ++ct)
#pragma unroll
        for (int j = 0; j < 4; ++j) {
            float p = __expf(sv[ct][j] - mnew);
            sv[ct][j] = p;
            rs += p;
        }
    rs += __shfl_xor(rs, 16);
    rs += __shfl_xor(rs, 32);
    lrun = lrun * sc + rs;
    mrun = mnew;

#pragma unroll
    for (int ct = 0; ct < 4; ++ct) {
        unsigned int w0 = f2b(sv[ct][0]) | ((unsigned int)f2b(sv[ct][1]) << 16);
        unsigned int w1 = f2b(sv[ct][2]) | ((unsigned int)f2b(sv[ct][3]) << 16);
        int off = q * 128 + ((ct * 32 + G * 8) ^ ((q & 7) << 4));
        *(unsigned long long*)((char*)Psw + off) =
            (unsigned long long)w0 | ((unsigned long long)w1 << 32);
    }
#pragma unroll
    for (int kvs = 0; kvs < 2; ++kvs) {
        int off = q * 128 + ((kvs * 64 + G * 16) ^ ((q & 7) << 4));
        pf[kvs] = *(const bf16x8*)((const char*)Psw + off);
    }
}

template <bool LO>
__device__ __forceinline__ void attn_step(
    const unsigned short* Ksb, const unsigned short* Vsb,
    unsigned short* Psh, unsigned short* Psl,
    const bf16x8 (&qfh)[4], const bf16x8 (&qfl)[4],
    f32x4 (&acch)[8], f32x4 (&accl)[8],
    float& mh, float& lh, float& ml, float& ll,
    int lane, int qh0, int ql0, int kvt, bool diagH, bool diagL)
{
    const int q = lane & 15, G = lane >> 4;

    // ---- QK^T (shared kf reads) ----
    f32x4 svh[4], svl[4];
    __builtin_amdgcn_s_setprio(1);
#pragma unroll
    for (int ct = 0; ct < 4; ++ct) {
        f32x4 sh = {}, sl = {};
#pragma unroll
        for (int ks = 0; ks < 4; ++ks) {
            int row = ct * 16 + q;
            int off = (row * 256 + ((ks * 64 + G * 16) ^ ((row & 7) << 4))) >> 1;
            bf16x8 kf = *(const bf16x8*)&Ksb[off];
            sh = __builtin_amdgcn_mfma_f32_16x16x32_bf16(kf, qfh[ks], sh, 0, 0, 0);
            if (LO) sl = __builtin_amdgcn_mfma_f32_16x16x32_bf16(kf, qfl[ks], sl, 0, 0, 0);
        }
        svh[ct] = sh;
        if (LO) svl[ct] = sl;
    }
    __builtin_amdgcn_s_setprio(0);

    // ---- causal masks ----
    if (diagH) {
        const int qg = qh0 + q;
#pragma unroll
        for (int ct = 0; ct < 4; ++ct)
#pragma unroll
            for (int j = 0; j < 4; ++j) {
                int kv = kvt * 64 + ct * 16 + G * 4 + j;
                if (kv > qg) svh[ct][j] = -1e30f;
            }
    }
    if (LO && diagL) {
        const int qg = ql0 + q;
#pragma unroll
        for (int ct = 0; ct < 4; ++ct)
#pragma unroll
            for (int j = 0; j < 4; ++j) {
                int kv = kvt * 64 + ct * 16 + G * 4 + j;
                if (kv > qg) svl[ct][j] = -1e30f;
            }
    }

    // ---- softmax + P pack (independent scalar chains; good ILP) ----
    bf16x8 pfh[2], pfl[2];
    softmax_pack(svh, acch, mh, lh, Psh, q, G, pfh);
    if (LO) softmax_pack(svl, accl, ml, ll, Psl, q, G, pfl);

    // ---- PV (shared vf reads) ----
    __builtin_amdgcn_s_setprio(1);
#pragma unroll
    for (int hdt = 0; hdt < 8; ++hdt)
#pragma unroll
        for (int kvs = 0; kvs < 2; ++kvs) {
            int row = hdt * 16 + q;
            int off = (row * 128 + ((kvs * 64 + G * 16) ^ ((row & 7) << 4))) >> 1;
            bf16x8 vf = *(const bf16x8*)&Vsb[off];
            acch[hdt] = __builtin_amdgcn_mfma_f32_16x16x32_bf16(vf, pfh[kvs], acch[hdt], 0, 0, 0);
            if (LO) accl[hdt] = __builtin_amdgcn_mfma_f32_16x16x32_bf16(vf, pfl[kvs], accl[hdt], 0, 0, 0);
        }
    __builtin_amdgcn_s_setprio(0);
}

__launch_bounds__(256)
__global__ void attn_fwd(const unsigned short* __restrict__ Q,
                         const unsigned short* __restrict__ K,
                         const unsigned short* __restrict__ Vt,
                         unsigned short* __restrict__ Out) {
    __shared__ unsigned short Ks[2][64 * 128];
    __shared__ unsigned short Vs[2][128 * 64];
    __shared__ unsigned short Ps[8][16 * 64];

    const int tid  = threadIdx.x;
    const int lane = tid & 63;
    const int w    = tid >> 6;

    const int id  = blockIdx.x;           // 0..511
    const int xcd = id & 7;
    const int j2  = id >> 3;
    const int bh  = xcd * 4 + (j2 >> 4);
    const int x   = j2 & 15;
    const int hiT = 31 - x;
    const int loT = x;
    const int qh0 = hiT * 64 + w * 16;
    const int ql0 = loT * 64 + w * 16;

    const char* Kbase = (const char*)(K  + (long)bh * SEQ * HEADD);
    const char* Vbase = (const char*)(Vt + (long)bh * HEADD * SEQ);

    bf16x8 qfh[4], qfl[4];
#pragma unroll
    for (int ks = 0; ks < 4; ++ks) {
        qfh[ks] = *(const bf16x8*)&Q[((long)bh * SEQ + qh0 + (lane & 15)) * HEADD + ks * 32 + (lane >> 4) * 8];
        qfl[ks] = *(const bf16x8*)&Q[((long)bh * SEQ + ql0 + (lane & 15)) * HEADD + ks * 32 + (lane >> 4) * 8];
    }

    f32x4 acch[8] = {}, accl[8] = {};
    float mh = -1e30f, lh = 0.f, ml = -1e30f, ll = 0.f;

#define STAGE(kvt, b) do {                                                              \
    _Pragma("unroll")                                                                   \
    for (int i = 0; i < 4; ++i) {                                                       \
        int c = tid + i * 256;                                                          \
        int rowk = c >> 4;                                                              \
        int cbk  = ((c & 15) * 16) ^ ((rowk & 7) << 4);                                 \
        gld_lds16(Kbase + (long)((kvt) * 64 + rowk) * 256 + cbk, (char*)Ks[b] + c * 16);\
        int rowv = c >> 3;                                                              \
        int cbv  = ((c & 7) * 16) ^ ((rowv & 7) << 4);                                  \
        gld_lds16(Vbase + (long)rowv * (SEQ * 2) + (kvt) * 128 + cbv, (char*)Vs[b] + c * 16); \
    } } while (0)

    STAGE(0, 0);
    __syncthreads();

    for (int kvt = 0; kvt <= hiT; ++kvt) {
        const int cur = kvt & 1;
        if (kvt < hiT) STAGE(kvt + 1, cur ^ 1);
        if (kvt <= loT)
            attn_step<true >(Ks[cur], Vs[cur], Ps[w], Ps[4 + w], qfh, qfl, acch, accl,
                             mh, lh, ml, ll, lane, qh0, ql0, kvt, kvt == hiT, kvt == loT);
        else
            attn_step<false>(Ks[cur], Vs[cur], Ps[w], Ps[4 + w], qfh, qfl, acch, accl,
                             mh, lh, ml, ll, lane, qh0, ql0, kvt, kvt == hiT, false);
        __syncthreads();
    }
#undef STAGE

    // ---- epilogue: acc is [d][q]; transpose via LDS (reuse Ks), coalesced store
    const int b = bh >> 4, nh = bh & 15;
    unsigned short* tbh = ((unsigned short*)Ks) + w * 2048;
    unsigned short* tbl = ((unsigned short*)Ks) + (4 + w) * 2048;
    {
        const float invh = 1.0f / lh, invl = 1.0f / ll;
        const int q = lane & 15, G = lane >> 4;
#pragma unroll
        for (int hdt = 0; hdt < 8; ++hdt) {
            int off = q * 256 + ((hdt * 32 + G * 8) ^ (q << 4));
            unsigned int h0 = f2b(acch[hdt][0] * invh) | ((unsigned int)f2b(acch[hdt][1] * invh) << 16);
            unsigned int h1 = f2b(acch[hdt][2] * invh) | ((unsigned int)f2b(acch[hdt][3] * invh) << 16);
            *(unsigned long long*)((char*)tbh + off) =
                (unsigned long long)h0 | ((unsigned long long)h1 << 32);
            unsigned int l0 = f2b(accl[hdt][0] * invl) | ((unsigned int)f2b(accl[hdt][1] * invl) << 16);
            unsigned int l1 = f2b(accl[hdt][2] * invl) | ((unsigned int)f2b(accl[hdt][3] * invl) << 16);
            *(unsigned long long*)((char*)tbl + off) =
                (unsigned long long)l0 | ((unsigned long long)l1 << 32);
        }
    }
    __syncthreads();
    {
        const int row = lane >> 2, sub = lane & 3;
        const long gh = ((long)(b * SEQ) + qh0 + row) * HDIM + nh * HEADD;
        const long gl = ((long)(b * SEQ) + ql0 + row) * HDIM + nh * HEADD;
#pragma unroll
        for (int r = 0; r < 4; ++r) {
            int off = row * 256 + ((r * 64 + sub * 16) ^ (row << 4));
            *(u16x8*)(Out + gh + r * 32 + sub * 8) = *(const u16x8*)((const char*)tbh + off);
            *(u16x8*)(Out + gl + r * 32 + sub * 8) = *(const u16x8*)((const char*)tbl + off);
        }
    }
}

// ---------------- launcher ----------------
extern "C" void kernel_launch(void* const* d_in, const int* in_sizes, int n_in,
                              void* d_out, int out_size, void* d_ws, size_t ws_size,
                              hipStream_t stream) {
    const float* hs = (const float*)d_in[0];
    const float* Wq = (const float*)d_in[2];
    const float* bq = (const float*)d_in[3];
    const float* Wk = (const float*)d_in[4];
    const float* bk = (const float*)d_in[5];
    const float* Wv = (const float*)d_in[6];
    const float* bv = (const float*)d_in[7];
    const float* Wo = (const float*)d_in[8];
    const float* bo = (const float*)d_in[9];
    float* out = (float*)d_out;

    char* ws = (char*)d_ws;
    const long MB = 1024L * 1024L;
    const float rs = 0.08838834764831845f; // 1/sqrt(128)
    dim3 gg(MTOT / 128, HDIM / 128);

    if (ws_size >= 96 * MB) {
        unsigned short* hsb = (unsigned short*)ws;
        unsigned short* wqb = (unsigned short*)(ws + 16 * MB);
        unsigned short* wkb = (unsigned short*)(ws + 24 * MB);
        unsigned short* wvb = (unsigned short*)(ws + 32 * MB);
        unsigned short* wob = (unsigned short*)(ws + 40 * MB);
        unsigned short* qb  = (unsigned short*)(ws + 48 * MB);
        unsigned short* kb  = (unsigned short*)(ws + 64 * MB);
        unsigned short* vtb = (unsigned short*)(ws + 80 * MB);
        unsigned short* aob = hsb;

        cvt5<<<dim3(1024, 1, 5), 256, 0, stream>>>(hs, Wq, Wk, Wv, Wo,
                                                   hsb, wqb, wkb, wvb, wob,
                                                   (long)MTOT * HDIM / 8, (long)HDIM * HDIM / 8);
        gemm_bt<0><<<gg, 256, 0, stream>>>(hsb, wqb, bq, qb,  HDIM, rs);
        gemm_bt<0><<<gg, 256, 0, stream>>>(hsb, wkb, bk, kb,  HDIM, 1.0f);
        gemm_bt<1><<<gg, 256, 0, stream>>>(hsb, wvb, bv, vtb, HDIM, 1.0f);
        attn_fwd<<<512, 256, 0, stream>>>(qb, kb, vtb, aob);
        gemm_bt<2><<<gg, 256, 0, stream>>>(aob, wob, bo, out, HDIM, 1.0f);
    } else {
        unsigned short* hsb = (unsigned short*)ws;
        unsigned short* wb  = (unsigned short*)(ws + 16 * MB);
        unsigned short* qb  = (unsigned short*)(ws + 24 * MB);
        unsigned short* kb  = (unsigned short*)(ws + 40 * MB);
        unsigned short* vtb = (unsigned short*)(ws + 56 * MB);
        unsigned short* aob = hsb;

        cvt_bf16<<<2048, 256, 0, stream>>>(hs, hsb, (long)MTOT * HDIM / 8);
        cvt_bf16<<<2048, 256, 0, stream>>>(Wq, wb, (long)HDIM * HDIM / 8);
        gemm_bt<0><<<gg, 256, 0, stream>>>(hsb, wb, bq, qb, HDIM, rs);
        cvt_bf16<<<2048, 256, 0, stream>>>(Wk, wb, (long)HDIM * HDIM / 8);
        gemm_bt<0><<<gg, 256, 0, stream>>>(hsb, wb, bk, kb, HDIM, 1.0f);
        cvt_bf16<<<2048, 256, 0, stream>>>(Wv, wb, (long)HDIM * HDIM / 8);
        gemm_bt<1><<<gg, 256, 0, stream>>>(hsb, wb, bv, vtb, HDIM, 1.0f);
        attn_fwd<<<512, 256, 0, stream>>>(qb, kb, vtb, aob);
        cvt_bf16<<<2048, 256, 0, stream>>>(Wo, wb, (long)HDIM * HDIM / 8);
        gemm_bt<2><<<gg, 256, 0, stream>>>(aob, wb, bo, out, HDIM, 1.0f);
    }
}

// Round 8
// 326.392 us; speedup vs baseline: 1.1182x; 1.1182x over previous
//
#include <hip/hip_runtime.h>
#include <hip/hip_bf16.h>

#define SEQ   2048
#define HDIM  2048
#define NHEAD 16
#define HEADD 128
#define BATCH 2
#define MTOT  (BATCH*SEQ)   // 4096
#define BH    (BATCH*NHEAD) // 32

typedef __attribute__((ext_vector_type(8))) __bf16 bf16x8;
typedef __attribute__((ext_vector_type(4))) float f32x4;
typedef __attribute__((ext_vector_type(16))) float f32x16;
typedef __attribute__((ext_vector_type(8))) unsigned short u16x8;

__device__ __forceinline__ unsigned short f2b(float f) {
    __bf16 h = (__bf16)f;
    return __builtin_bit_cast(unsigned short, h);
}

__device__ __forceinline__ void gld_lds16(const void* gptr, void* ldsptr) {
    __builtin_amdgcn_global_load_lds(
        (const __attribute__((address_space(1))) unsigned int*)gptr,
        (__attribute__((address_space(3))) unsigned int*)ldsptr,
        16, 0, 0);
}

// ---------------- f32 -> bf16 convert (vectorized, grid-stride) ----------------
__global__ void cvt_bf16(const float* __restrict__ src, unsigned short* __restrict__ dst, long n8) {
    long i = blockIdx.x * (long)blockDim.x + threadIdx.x;
    long stride = (long)gridDim.x * blockDim.x;
    for (; i < n8; i += stride) {
        f32x4 a = *(const f32x4*)(src + i * 8);
        f32x4 b = *(const f32x4*)(src + i * 8 + 4);
        u16x8 o;
#pragma unroll
        for (int j = 0; j < 4; ++j) { o[j] = f2b(a[j]); o[4 + j] = f2b(b[j]); }
        *(u16x8*)(dst + i * 8) = o;
    }
}

// fused 5-way convert
__global__ void cvt5(const float* __restrict__ s0, const float* __restrict__ s1,
                     const float* __restrict__ s2, const float* __restrict__ s3,
                     const float* __restrict__ s4,
                     unsigned short* __restrict__ d0, unsigned short* __restrict__ d1,
                     unsigned short* __restrict__ d2, unsigned short* __restrict__ d3,
                     unsigned short* __restrict__ d4,
                     long n0, long n1) {
    const float* s; unsigned short* d; long n;
    switch (blockIdx.z) {
        case 0: s = s0; d = d0; n = n0; break;
        case 1: s = s1; d = d1; n = n1; break;
        case 2: s = s2; d = d2; n = n1; break;
        case 3: s = s3; d = d3; n = n1; break;
        default: s = s4; d = d4; n = n1; break;
    }
    long i = blockIdx.x * (long)blockDim.x + threadIdx.x;
    long stride = (long)gridDim.x * blockDim.x;
    for (; i < n; i += stride) {
        f32x4 a = *(const f32x4*)(s + i * 8);
        f32x4 b = *(const f32x4*)(s + i * 8 + 4);
        u16x8 o;
#pragma unroll
        for (int j = 0; j < 4; ++j) { o[j] = f2b(a[j]); o[4 + j] = f2b(b[j]); }
        *(u16x8*)(d + i * 8) = o;
    }
}

// ---------------- GEMM: C[m][n] = A[m][:] . Bw[n][:] + bias[n]  (B^T layout) ----
template <int MODE>
__launch_bounds__(256)
__global__ void gemm_bt(const unsigned short* __restrict__ A,
                        const unsigned short* __restrict__ Bw,
                        const float* __restrict__ bias,
                        void* __restrict__ Cout,
                        int Kc, float scale) {
    __shared__ unsigned short As[128 * 32];
    __shared__ unsigned short Bs[128 * 32];
    const int tid  = threadIdx.x;
    const int lane = tid & 63;
    const int w    = tid >> 6;

    const int wgid = blockIdx.y * gridDim.x + blockIdx.x;
    const int cpx  = (gridDim.x * gridDim.y) >> 3;
    const int swz  = (wgid & 7) * cpx + (wgid >> 3);
    const int m0 = (swz % gridDim.x) * 128, n0 = (swz / gridDim.x) * 128;

    const int wr = (w >> 1) * 64, wc = (w & 1) * 64;
    const long rowBytes = (long)Kc * 2;

    f32x4 acc[4][4] = {};

    const int kIters = Kc >> 5;
    for (int kt = 0; kt < kIters; ++kt) {
        const long kb = (long)kt * 64;
#pragma unroll
        for (int i = 0; i < 2; ++i) {
            int c = tid + i * 256;
            int row = c >> 2;
            int cb  = (c & 3) * 16;
            gld_lds16((const char*)A  + (long)(m0 + row) * rowBytes + kb + cb, (char*)As + c * 16);
            gld_lds16((const char*)Bw + (long)(n0 + row) * rowBytes + kb + cb, (char*)Bs + c * 16);
        }
        __syncthreads();
        bf16x8 af[4], bfr[4];
#pragma unroll
        for (int f = 0; f < 4; ++f) {
            af[f]  = *(const bf16x8*)&As[(wr + f * 16 + (lane & 15)) * 32 + (lane >> 4) * 8];
            bfr[f] = *(const bf16x8*)&Bs[(wc + f * 16 + (lane & 15)) * 32 + (lane >> 4) * 8];
        }
#pragma unroll
        for (int mf = 0; mf < 4; ++mf)
#pragma unroll
            for (int nf = 0; nf < 4; ++nf)
                acc[mf][nf] = __builtin_amdgcn_mfma_f32_16x16x32_bf16(af[mf], bfr[nf], acc[mf][nf], 0, 0, 0);
        __syncthreads();
    }

#pragma unroll
    for (int mf = 0; mf < 4; ++mf) {
#pragma unroll
        for (int nf = 0; nf < 4; ++nf) {
            int n = n0 + wc + nf * 16 + (lane & 15);
            float bv = bias[n];
#pragma unroll
            for (int j = 0; j < 4; ++j) {
                int m = m0 + wr + mf * 16 + (lane >> 4) * 4 + j;
                float v = (acc[mf][nf][j] + bv) * scale;
                if (MODE == 0) {
                    int b = m >> 11, s = m & 2047;
                    int nh = n >> 7, hd = n & 127;
                    ((unsigned short*)Cout)[((long)(b * NHEAD + nh) * SEQ + s) * HEADD + hd] = f2b(v);
                } else if (MODE == 1) {
                    int b = m >> 11, s = m & 2047;
                    int nh = n >> 7, hd = n & 127;
                    ((unsigned short*)Cout)[((long)(b * NHEAD + nh) * HEADD + hd) * SEQ + s] = f2b(v);
                } else {
                    ((float*)Cout)[(long)m * HDIM + n] = v;
                }
            }
        }
    }
}

// ---------------- causal flash attention: 32x32x16 MFMA, 32 q-rows/wave ------
// S^T = mfma32(kf, qf): C col = q = lane&31, row = kv = (r&3)+8*(r>>2)+4*(lane>>5).
// PV:  O^T = mfma32(vf, pf): C col = q, row = d.
// Per step, a wave reads the whole K/V tile ONCE for 32 q-rows (16 FLOP/LDS-byte).

__device__ __forceinline__ void attn_step32(
    const unsigned short* Ksb, const unsigned short* Vsb, char* Psw,
    const bf16x8 (&qf)[8], f32x16 (&acc)[4], float& mrun, float& lrun,
    int lane, int q0w, int kvt, bool diag)
{
    const int ql = lane & 31;
    const int hi = lane >> 5;

    // ---- QK^T: S^T fragments (kvb = 0,1 -> kv 0-31, 32-63) ----
    f32x16 sv[2];
#pragma unroll
    for (int kvb = 0; kvb < 2; ++kvb) {
        f32x16 s = {};
        const int row = kvb * 32 + ql;
        const int sw  = (row & 7) << 4;
#pragma unroll
        for (int kc = 0; kc < 8; ++kc) {
            int off = (row * 256 + ((kc * 32 + hi * 16) ^ sw)) >> 1;
            bf16x8 kf = *(const bf16x8*)&Ksb[off];
            s = __builtin_amdgcn_mfma_f32_32x32x16_bf16(kf, qf[kc], s, 0, 0, 0);
        }
        sv[kvb] = s;
    }

    // ---- causal mask ----
    if (diag) {
        const int qg = q0w + ql;
#pragma unroll
        for (int kvb = 0; kvb < 2; ++kvb)
#pragma unroll
            for (int r = 0; r < 16; ++r) {
                int kv = kvt * 64 + kvb * 32 + (r & 3) + 8 * (r >> 2) + 4 * hi;
                if (kv > qg) sv[kvb][r] = -1e30f;
            }
    }

    // ---- online softmax: lane owns q-column; 32 in-lane values + 1 shfl ----
    float tmax = sv[0][0];
#pragma unroll
    for (int kvb = 0; kvb < 2; ++kvb)
#pragma unroll
        for (int r = 0; r < 16; ++r) tmax = fmaxf(tmax, sv[kvb][r]);
    tmax = fmaxf(tmax, __shfl_xor(tmax, 32));

    float mnew = mrun, sc = 1.0f;
    if (__any(tmax > mrun + 8.0f)) {   // defer-max (T13)
        mnew = fmaxf(mrun, tmax);
        sc = __expf(mrun - mnew);
#pragma unroll
        for (int db = 0; db < 4; ++db) acc[db] *= sc;
    }
    float rs = 0.f;
#pragma unroll
    for (int kvb = 0; kvb < 2; ++kvb)
#pragma unroll
        for (int r = 0; r < 16; ++r) {
            float p = __expf(sv[kvb][r] - mnew);
            sv[kvb][r] = p;
            rs += p;
        }
    rs += __shfl_xor(rs, 32);
    lrun = lrun * sc + rs;
    mrun = mnew;

    // ---- P -> LDS [q][kv] (swizzled), 8x ds_write_b64 ----
#pragma unroll
    for (int kvb = 0; kvb < 2; ++kvb)
#pragma unroll
        for (int m = 0; m < 4; ++m) {
            unsigned int w0 = f2b(sv[kvb][m * 4 + 0]) | ((unsigned int)f2b(sv[kvb][m * 4 + 1]) << 16);
            unsigned int w1 = f2b(sv[kvb][m * 4 + 2]) | ((unsigned int)f2b(sv[kvb][m * 4 + 3]) << 16);
            int off = ql * 128 + ((kvb * 64 + m * 16 + hi * 8) ^ ((ql & 7) << 4));
            *(unsigned long long*)(Psw + off) =
                (unsigned long long)w0 | ((unsigned long long)w1 << 32);
        }
    // ---- P re-read as PV B-operand (lane reads own q-row) ----
    bf16x8 pf[4];
#pragma unroll
    for (int kc2 = 0; kc2 < 4; ++kc2) {
        int off = ql * 128 + ((kc2 * 32 + hi * 16) ^ ((ql & 7) << 4));
        pf[kc2] = *(const bf16x8*)(Psw + off);
    }

    // ---- PV: O^T += V^T . P ----
#pragma unroll
    for (int db = 0; db < 4; ++db) {
        const int row = db * 32 + ql;
        const int sw  = (row & 7) << 4;
#pragma unroll
        for (int kc2 = 0; kc2 < 4; ++kc2) {
            int off = (row * 128 + ((kc2 * 32 + hi * 16) ^ sw)) >> 1;
            bf16x8 vf = *(const bf16x8*)&Vsb[off];
            acc[db] = __builtin_amdgcn_mfma_f32_32x32x16_bf16(vf, pf[kc2], acc[db], 0, 0, 0);
        }
    }
}

// epilogue: normalize acc (O^T [d][q]) -> per-wave LDS transpose -> coalesced store
__device__ __forceinline__ void attn_epilogue(
    const f32x16 (&acc)[4], float lrun, char* Psw,
    unsigned short* __restrict__ Out, int b, int nh, int q0w, int lane)
{
    const int ql = lane & 31, hi = lane >> 5;
    const float inv = 1.0f / lrun;
#pragma unroll
    for (int db = 0; db < 4; ++db)
#pragma unroll
        for (int m = 0; m < 4; ++m) {
            unsigned int w0 = f2b(acc[db][m * 4 + 0] * inv) | ((unsigned int)f2b(acc[db][m * 4 + 1] * inv) << 16);
            unsigned int w1 = f2b(acc[db][m * 4 + 2] * inv) | ((unsigned int)f2b(acc[db][m * 4 + 3] * inv) << 16);
            int off = ql * 256 + ((db * 64 + m * 16 + hi * 8) ^ ((ql & 7) << 4));
            *(unsigned long long*)(Psw + off) =
                (unsigned long long)w0 | ((unsigned long long)w1 << 32);
        }
    __syncthreads();
#pragma unroll
    for (int it = 0; it < 8; ++it) {
        int row = it * 4 + (lane >> 4);
        int sub = lane & 15;
        int off = row * 256 + ((sub * 16) ^ ((row & 7) << 4));
        *(u16x8*)(Out + ((long)(b * SEQ) + q0w + row) * HDIM + nh * HEADD + sub * 8) =
            *(const u16x8*)(Psw + off);
    }
}

__launch_bounds__(256)
__global__ void attn_fwd(const unsigned short* __restrict__ Q,
                         const unsigned short* __restrict__ K,
                         const unsigned short* __restrict__ Vt,
                         unsigned short* __restrict__ Out) {
    __shared__ unsigned short Ks[2][64 * 128];   // 32 KB double-buffered K tile
    __shared__ unsigned short Vs[2][128 * 64];   // 32 KB double-buffered Vt tile
    __shared__ unsigned short Ps[4][4096];       // 32 KB: 8 KB per-wave P / epilogue scratch

    const int tid  = threadIdx.x;
    const int lane = tid & 63;
    const int w    = tid >> 6;

    // 256 blocks: xcd-grouped heads; pair 128-row q-tiles (15-x, x) for balance
    const int id  = blockIdx.x;
    const int xcd = id & 7;
    const int j   = id >> 3;              // 0..31
    const int bh  = xcd * 4 + (j >> 3);   // 0..31
    const int x   = j & 7;                // 0..7
    const int hiT = 15 - x;               // 128-row tile 8..15
    const int loT = x;                    // 0..7
    const int nA  = 2 * hiT + 2;
    const int nB  = 2 * loT + 2;
    const int q0A = hiT * 128 + w * 32;
    const int q0B = loT * 128 + w * 32;

    const char* Kbase = (const char*)(K  + (long)bh * SEQ * HEADD);
    const char* Vbase = (const char*)(Vt + (long)bh * HEADD * SEQ);
    char* Psw = (char*)&Ps[w][0];

    bf16x8 qfA[8], qfB[8];
#pragma unroll
    for (int kc = 0; kc < 8; ++kc) {
        qfA[kc] = *(const bf16x8*)&Q[((long)bh * SEQ + q0A + (lane & 31)) * HEADD + kc * 16 + (lane >> 5) * 8];
        qfB[kc] = *(const bf16x8*)&Q[((long)bh * SEQ + q0B + (lane & 31)) * HEADD + kc * 16 + (lane >> 5) * 8];
    }

#define STAGE(kvt, b) do {                                                              \
    _Pragma("unroll")                                                                   \
    for (int i = 0; i < 4; ++i) {                                                       \
        int c = tid + i * 256;                                                          \
        int rowk = c >> 4;                                                              \
        int cbk  = ((c & 15) * 16) ^ ((rowk & 7) << 4);                                 \
        gld_lds16(Kbase + (long)((kvt) * 64 + rowk) * 256 + cbk, (char*)Ks[b] + c * 16);\
        int rowv = c >> 3;                                                              \
        int cbv  = ((c & 7) * 16) ^ ((rowv & 7) << 4);                                  \
        gld_lds16(Vbase + (long)rowv * (SEQ * 2) + (kvt) * 128 + cbv, (char*)Vs[b] + c * 16); \
    } } while (0)

    const int b = bh >> 4, nh = bh & 15;
    int buf = 0;

    STAGE(0, 0);
    __syncthreads();

    // ---- phase A: hi tile ----
    {
        f32x16 acc[4] = {};
        float mrun = -1e30f, lrun = 0.f;
        for (int s = 0; s < nA; ++s) {
            if (s + 1 < nA) STAGE(s + 1, buf ^ 1);
            else            STAGE(0, buf ^ 1);           // prefetch lo tile kvt=0
            attn_step32(Ks[buf], Vs[buf], Psw, qfA, acc, mrun, lrun,
                        lane, q0A, s, s * 64 + 63 > q0A);
            __syncthreads();
            buf ^= 1;
        }
        attn_epilogue(acc, lrun, Psw, Out, b, nh, q0A, lane);
    }

    // ---- phase B: lo tile ----
    {
        f32x16 acc[4] = {};
        float mrun = -1e30f, lrun = 0.f;
        for (int s = 0; s < nB; ++s) {
            if (s + 1 < nB) STAGE(s + 1, buf ^ 1);
            attn_step32(Ks[buf], Vs[buf], Psw, qfB, acc, mrun, lrun,
                        lane, q0B, s, s * 64 + 63 > q0B);
            __syncthreads();
            buf ^= 1;
        }
        attn_epilogue(acc, lrun, Psw, Out, b, nh, q0B, lane);
    }
#undef STAGE
}

// ---------------- launcher ----------------
extern "C" void kernel_launch(void* const* d_in, const int* in_sizes, int n_in,
                              void* d_out, int out_size, void* d_ws, size_t ws_size,
                              hipStream_t stream) {
    const float* hs = (const float*)d_in[0];
    const float* Wq = (const float*)d_in[2];
    const float* bq = (const float*)d_in[3];
    const float* Wk = (const float*)d_in[4];
    const float* bk = (const float*)d_in[5];
    const float* Wv = (const float*)d_in[6];
    const float* bv = (const float*)d_in[7];
    const float* Wo = (const float*)d_in[8];
    const float* bo = (const float*)d_in[9];
    float* out = (float*)d_out;

    char* ws = (char*)d_ws;
    const long MB = 1024L * 1024L;
    const float rs = 0.08838834764831845f; // 1/sqrt(128)
    dim3 gg(MTOT / 128, HDIM / 128);

    if (ws_size >= 96 * MB) {
        unsigned short* hsb = (unsigned short*)ws;
        unsigned short* wqb = (unsigned short*)(ws + 16 * MB);
        unsigned short* wkb = (unsigned short*)(ws + 24 * MB);
        unsigned short* wvb = (unsigned short*)(ws + 32 * MB);
        unsigned short* wob = (unsigned short*)(ws + 40 * MB);
        unsigned short* qb  = (unsigned short*)(ws + 48 * MB);
        unsigned short* kb  = (unsigned short*)(ws + 64 * MB);
        unsigned short* vtb = (unsigned short*)(ws + 80 * MB);
        unsigned short* aob = hsb;

        cvt5<<<dim3(1024, 1, 5), 256, 0, stream>>>(hs, Wq, Wk, Wv, Wo,
                                                   hsb, wqb, wkb, wvb, wob,
                                                   (long)MTOT * HDIM / 8, (long)HDIM * HDIM / 8);
        gemm_bt<0><<<gg, 256, 0, stream>>>(hsb, wqb, bq, qb,  HDIM, rs);
        gemm_bt<0><<<gg, 256, 0, stream>>>(hsb, wkb, bk, kb,  HDIM, 1.0f);
        gemm_bt<1><<<gg, 256, 0, stream>>>(hsb, wvb, bv, vtb, HDIM, 1.0f);
        attn_fwd<<<256, 256, 0, stream>>>(qb, kb, vtb, aob);
        gemm_bt<2><<<gg, 256, 0, stream>>>(aob, wob, bo, out, HDIM, 1.0f);
    } else {
        unsigned short* hsb = (unsigned short*)ws;
        unsigned short* wb  = (unsigned short*)(ws + 16 * MB);
        unsigned short* qb  = (unsigned short*)(ws + 24 * MB);
        unsigned short* kb  = (unsigned short*)(ws + 40 * MB);
        unsigned short* vtb = (unsigned short*)(ws + 56 * MB);
        unsigned short* aob = hsb;

        cvt_bf16<<<2048, 256, 0, stream>>>(hs, hsb, (long)MTOT * HDIM / 8);
        cvt_bf16<<<2048, 256, 0, stream>>>(Wq, wb, (long)HDIM * HDIM / 8);
        gemm_bt<0><<<gg, 256, 0, stream>>>(hsb, wb, bq, qb, HDIM, rs);
        cvt_bf16<<<2048, 256, 0, stream>>>(Wk, wb, (long)HDIM * HDIM / 8);
        gemm_bt<0><<<gg, 256, 0, stream>>>(hsb, wb, bk, kb, HDIM, 1.0f);
        cvt_bf16<<<2048, 256, 0, stream>>>(Wv, wb, (long)HDIM * HDIM / 8);
        gemm_bt<1><<<gg, 256, 0, stream>>>(hsb, wb, bv, vtb, HDIM, 1.0f);
        attn_fwd<<<256, 256, 0, stream>>>(qb, kb, vtb, aob);
        cvt_bf16<<<2048, 256, 0, stream>>>(Wo, wb, (long)HDIM * HDIM / 8);
        gemm_bt<2><<<gg, 256, 0, stream>>>(aob, wb, bo, out, HDIM, 1.0f);
    }
}